// Round 14
// baseline (331.857 us; speedup 1.0000x reference)
//
#include <hip/hip_runtime.h>
#include <math.h>

#define D 2048
#define K 8
#define BLOCK 512     // 8 independent waves; wave owns a whole row (lane = 32 cols)
#define RPW 4         // contiguous rows per wave

typedef __fp16 h2 __attribute__((ext_vector_type(2)));
typedef __fp16 h4 __attribute__((ext_vector_type(4)));

__device__ __forceinline__ float rcp_fast(float x) {
    return __builtin_amdgcn_rcpf(x);
}

#if __has_builtin(__builtin_amdgcn_fdot2)
#define FDOT2(a, b, c) __builtin_amdgcn_fdot2((a), (b), (c), false)
#else
__device__ __forceinline__ float fdot2_emul(h2 a, h2 b, float c) {
    return fmaf((float)a[0], (float)b[0], fmaf((float)a[1], (float)b[1], c));
}
#define FDOT2 fdot2_emul
#endif

// 0.5*y*(1+tanh(c*(y+0.044715*y^3))) == y * sigmoid(2c*(y+0.044715*y^3))
__device__ __forceinline__ float gelu_tanh_fast(float y) {
    const float nc = -2.3022078977f; // -2*sqrt(2/pi)*log2(e)
    float w = y * fmaf(0.044715f, y * y, 1.0f);
    return y * rcp_fast(1.0f + exp2f(nc * w));
}

__device__ __forceinline__ float dot4f(const float4& a, const float4& b) {
    return fmaf(a.w, b.w, fmaf(a.z, b.z, fmaf(a.y, b.y, a.x * b.x)));
}

// Fold step: combine slots x (bit=0) and y (bit=1) across lanes differing in `m`.
#define FOLDSTEP(x, y, m)                                   \
    {                                                       \
        float _k = (lane & (m)) ? (y) : (x);                \
        float _o = (lane & (m)) ? (x) : (y);                \
        x = _k + __shfl_xor(_o, (m));                       \
    }

__global__ __launch_bounds__(BLOCK, 8)   // cap 64 VGPR -> 8 waves/SIMD
void novelty_gelu_wave(const float* __restrict__ x,
                       const float* __restrict__ P,
                       const float* __restrict__ plog_tau,
                       const float* __restrict__ plog_blend,
                       float* __restrict__ out,
                       int nrows)
{
    __shared__ h4    pf[K * 512];   // 32 KB: proto k, chunk-lane h4 index
    __shared__ float s_inv[K];

    const int tid  = threadIdx.x;
    const int wave = tid >> 6;
    const int lane = tid & 63;

    // ---- prototype inv-norms: wave w handles proto w (8 waves = 8 protos)
    {
        const float* pr = P + wave * D;
        float s = 0.f;
        #pragma unroll
        for (int j = 0; j < 8; ++j) {
            float4 p = *(const float4*)(pr + (j * 64 + lane) * 4);
            s += dot4f(p, p);
        }
        #pragma unroll
        for (int m = 1; m < 64; m <<= 1) s += __shfl_xor(s, m);
        if (lane == 0) s_inv[wave] = 1.0f / fmaxf(sqrtf(s), 1e-8f);
    }
    __syncthreads();

    // ---- pf fill: thread t writes proto k's h4 chunk t (lane-stride-8B, dense)
    #pragma unroll
    for (int k = 0; k < K; ++k) {
        const float inv = s_inv[k];
        float4 p = *(const float4*)(P + k * D + tid * 4);
        h2 lo = __builtin_amdgcn_cvt_pkrtz(p.x * inv, p.y * inv);
        h2 hi = __builtin_amdgcn_cvt_pkrtz(p.z * inv, p.w * inv);
        pf[k * 512 + tid] = __builtin_shufflevector(lo, hi, 0, 1, 2, 3);
    }
    __syncthreads();
    // ---- from here on: every wave fully independent, no barriers, no LDS writes

    const float tau   = __expf(plog_tau[0]);
    const float alpha = 1.0f / (1.0f + __expf(-plog_blend[0]));
    const float oma   = 1.0f - alpha;

    const int wid = blockIdx.x * (BLOCK / 64) + wave;
    int row = wid * RPW;
    int limit = row + RPW;
    if (limit > nrows) limit = nrows;

    for (; row < limit; ++row) {
        const float* xr = x + (size_t)row * D;

        // load whole row: 8 coalesced dwordx4 per lane, convert to f16 as they land
        float4 v[8];
        #pragma unroll
        for (int c = 0; c < 8; ++c)
            v[c] = *(const float4*)(xr + (c * 64 + lane) * 4);

        h2 xh[16];
        #pragma unroll
        for (int c = 0; c < 8; ++c) {
            xh[2 * c]     = __builtin_amdgcn_cvt_pkrtz(v[c].x, v[c].y);
            xh[2 * c + 1] = __builtin_amdgcn_cvt_pkrtz(v[c].z, v[c].w);
        }

        // per-lane partials: ssq + 8 dots, pf streamed from LDS
        float ssq = 0.f;
        float dt[K];
        #pragma unroll
        for (int k = 0; k < K; ++k) dt[k] = 0.f;
        #pragma unroll
        for (int c = 0; c < 8; ++c) {
            ssq = FDOT2(xh[2 * c],     xh[2 * c],     ssq);
            ssq = FDOT2(xh[2 * c + 1], xh[2 * c + 1], ssq);
            #pragma unroll
            for (int k = 0; k < K; ++k) {
                h4 p  = pf[k * 512 + c * 64 + lane];
                h2 lo = __builtin_shufflevector(p, p, 0, 1);
                h2 hi = __builtin_shufflevector(p, p, 2, 3);
                dt[k] = FDOT2(xh[2 * c],     lo, dt[k]);
                dt[k] = FDOT2(xh[2 * c + 1], hi, dt[k]);
            }
        }

        // wave-local full reduction: 19 swizzles, no LDS, no barrier
        FOLDSTEP(dt[0], dt[1], 1);
        FOLDSTEP(dt[2], dt[3], 1);
        FOLDSTEP(dt[4], dt[5], 1);
        FOLDSTEP(dt[6], dt[7], 1);
        FOLDSTEP(dt[0], dt[2], 2);
        FOLDSTEP(dt[4], dt[6], 2);
        FOLDSTEP(dt[0], dt[4], 4);
        float vd = dt[0];
        vd += __shfl_xor(vd, 8);
        vd += __shfl_xor(vd, 16);
        vd += __shfl_xor(vd, 32);              // lane l: full-row dot[l&7]
        float dmax = vd;                        // max over the 8 slots
        dmax = fmaxf(dmax, __shfl_xor(dmax, 1));
        dmax = fmaxf(dmax, __shfl_xor(dmax, 2));
        dmax = fmaxf(dmax, __shfl_xor(dmax, 4));
        #pragma unroll
        for (int m = 1; m < 64; m <<= 1) ssq += __shfl_xor(ssq, m);

        const float inv_nx = 1.0f / fmaxf(sqrtf(ssq), 1e-8f);
        float sim = fminf(1.0f, fmaxf(-1.0f, dmax * inv_nx));
        float md  = fminf(fmaxf(1.0f - sim, 0.0f), 2.0f);
        float scale = oma + alpha * (1.0f - __expf(-tau * md));
        scale = fminf(fmaxf(scale, 0.1f), 10.0f);

        // epilogue straight from f16 row registers
        float* outr = out + (size_t)row * D;
        #pragma unroll
        for (int c = 0; c < 8; ++c) {
            float4 o;
            o.x = gelu_tanh_fast((float)xh[2 * c][0]     * scale);
            o.y = gelu_tanh_fast((float)xh[2 * c][1]     * scale);
            o.z = gelu_tanh_fast((float)xh[2 * c + 1][0] * scale);
            o.w = gelu_tanh_fast((float)xh[2 * c + 1][1] * scale);
            *(float4*)(outr + (c * 64 + lane) * 4) = o;
        }
    }
}

extern "C" void kernel_launch(void* const* d_in, const int* in_sizes, int n_in,
                              void* d_out, int out_size, void* d_ws, size_t ws_size,
                              hipStream_t stream) {
    const float* x  = (const float*)d_in[0];
    const float* P  = (const float*)d_in[1];
    const float* lt = (const float*)d_in[2];
    const float* lb = (const float*)d_in[3];
    float* out = (float*)d_out;

    const int nrows = in_sizes[0] / D;             // 32768
    const int waves = BLOCK / 64;                  // 8
    int grid = (nrows + waves * RPW - 1) / (waves * RPW);   // 1024

    novelty_gelu_wave<<<grid, BLOCK, 0, stream>>>(x, P, lt, lb, out, nrows);
}

// Round 15
// 207.070 us; speedup vs baseline: 1.6026x; 1.6026x over previous
//
#include <hip/hip_runtime.h>
#include <math.h>

#define D 2048
#define K 8
#define BLOCK 512     // 8 independent waves; wave owns a whole row (lane = 32 cols)
#define RPW 4         // contiguous rows per wave

typedef __fp16 h2 __attribute__((ext_vector_type(2)));
typedef __fp16 h4 __attribute__((ext_vector_type(4)));

__device__ __forceinline__ float rcp_fast(float x) {
    return __builtin_amdgcn_rcpf(x);
}

#if __has_builtin(__builtin_amdgcn_fdot2)
#define FDOT2(a, b, c) __builtin_amdgcn_fdot2((a), (b), (c), false)
#else
__device__ __forceinline__ float fdot2_emul(h2 a, h2 b, float c) {
    return fmaf((float)a[0], (float)b[0], fmaf((float)a[1], (float)b[1], c));
}
#define FDOT2 fdot2_emul
#endif

// 0.5*y*(1+tanh(c*(y+0.044715*y^3))) == y * sigmoid(2c*(y+0.044715*y^3))
__device__ __forceinline__ float gelu_tanh_fast(float y) {
    const float nc = -2.3022078977f; // -2*sqrt(2/pi)*log2(e)
    float w = y * fmaf(0.044715f, y * y, 1.0f);
    return y * rcp_fast(1.0f + exp2f(nc * w));
}

__device__ __forceinline__ float dot4f(const float4& a, const float4& b) {
    return fmaf(a.w, b.w, fmaf(a.z, b.z, fmaf(a.y, b.y, a.x * b.x)));
}

// Fold step: combine slots x (bit=0) and y (bit=1) across lanes differing in `m`.
#define FOLDSTEP(x, y, m)                                   \
    {                                                       \
        float _k = (lane & (m)) ? (y) : (x);                \
        float _o = (lane & (m)) ? (x) : (y);                \
        x = _k + __shfl_xor(_o, (m));                       \
    }

__global__ __launch_bounds__(BLOCK, 4)   // honest bound: 128 VGPR cap, no spill
void novelty_gelu_wave(const float* __restrict__ x,
                       const float* __restrict__ P,
                       const float* __restrict__ plog_tau,
                       const float* __restrict__ plog_blend,
                       float* __restrict__ out,
                       int nrows)
{
    __shared__ h4    pf[K * 512];   // 32 KB: proto k, chunk-lane h4 index
    __shared__ float s_inv[K];

    const int tid  = threadIdx.x;
    const int wave = tid >> 6;
    const int lane = tid & 63;

    // ---- prototype inv-norms: wave w handles proto w (8 waves = 8 protos)
    {
        const float* pr = P + wave * D;
        float s = 0.f;
        #pragma unroll
        for (int j = 0; j < 8; ++j) {
            float4 p = *(const float4*)(pr + (j * 64 + lane) * 4);
            s += dot4f(p, p);
        }
        #pragma unroll
        for (int m = 1; m < 64; m <<= 1) s += __shfl_xor(s, m);
        if (lane == 0) s_inv[wave] = 1.0f / fmaxf(sqrtf(s), 1e-8f);
    }
    __syncthreads();

    // ---- pf fill: thread t writes proto k's h4 chunk t (lane-stride-8B, dense)
    #pragma unroll
    for (int k = 0; k < K; ++k) {
        const float inv = s_inv[k];
        float4 p = *(const float4*)(P + k * D + tid * 4);
        h2 lo = __builtin_amdgcn_cvt_pkrtz(p.x * inv, p.y * inv);
        h2 hi = __builtin_amdgcn_cvt_pkrtz(p.z * inv, p.w * inv);
        pf[k * 512 + tid] = __builtin_shufflevector(lo, hi, 0, 1, 2, 3);
    }
    __syncthreads();
    // ---- from here on: every wave fully independent, no barriers, no LDS writes

    const float tau   = __expf(plog_tau[0]);
    const float alpha = 1.0f / (1.0f + __expf(-plog_blend[0]));
    const float oma   = 1.0f - alpha;

    const int wid = blockIdx.x * (BLOCK / 64) + wave;
    int row = wid * RPW;
    int limit = row + RPW;
    if (limit > nrows) limit = nrows;

    for (; row < limit; ++row) {
        const float* xr = x + (size_t)row * D;

        // load whole row: 8 coalesced dwordx4 per lane (all in flight together)
        float4 v[8];
        #pragma unroll
        for (int c = 0; c < 8; ++c)
            v[c] = *(const float4*)(xr + (c * 64 + lane) * 4);

        h2 xh[16];
        #pragma unroll
        for (int c = 0; c < 8; ++c) {
            xh[2 * c]     = __builtin_amdgcn_cvt_pkrtz(v[c].x, v[c].y);
            xh[2 * c + 1] = __builtin_amdgcn_cvt_pkrtz(v[c].z, v[c].w);
        }

        // per-lane partials: ssq + 8 dots, pf streamed from LDS
        float ssq = 0.f;
        float dt[K];
        #pragma unroll
        for (int k = 0; k < K; ++k) dt[k] = 0.f;
        #pragma unroll
        for (int c = 0; c < 8; ++c) {
            ssq = FDOT2(xh[2 * c],     xh[2 * c],     ssq);
            ssq = FDOT2(xh[2 * c + 1], xh[2 * c + 1], ssq);
            #pragma unroll
            for (int k = 0; k < K; ++k) {
                h4 p  = pf[k * 512 + c * 64 + lane];
                h2 lo = __builtin_shufflevector(p, p, 0, 1);
                h2 hi = __builtin_shufflevector(p, p, 2, 3);
                dt[k] = FDOT2(xh[2 * c],     lo, dt[k]);
                dt[k] = FDOT2(xh[2 * c + 1], hi, dt[k]);
            }
        }

        // wave-local full reduction: 19 swizzles, no LDS, no barrier
        FOLDSTEP(dt[0], dt[1], 1);
        FOLDSTEP(dt[2], dt[3], 1);
        FOLDSTEP(dt[4], dt[5], 1);
        FOLDSTEP(dt[6], dt[7], 1);
        FOLDSTEP(dt[0], dt[2], 2);
        FOLDSTEP(dt[4], dt[6], 2);
        FOLDSTEP(dt[0], dt[4], 4);
        float vd = dt[0];
        vd += __shfl_xor(vd, 8);
        vd += __shfl_xor(vd, 16);
        vd += __shfl_xor(vd, 32);              // lane l: full-row dot[l&7]
        float dmax = vd;                        // max over the 8 slots
        dmax = fmaxf(dmax, __shfl_xor(dmax, 1));
        dmax = fmaxf(dmax, __shfl_xor(dmax, 2));
        dmax = fmaxf(dmax, __shfl_xor(dmax, 4));
        #pragma unroll
        for (int m = 1; m < 64; m <<= 1) ssq += __shfl_xor(ssq, m);

        const float inv_nx = 1.0f / fmaxf(sqrtf(ssq), 1e-8f);
        float sim = fminf(1.0f, fmaxf(-1.0f, dmax * inv_nx));
        float md  = fminf(fmaxf(1.0f - sim, 0.0f), 2.0f);
        float scale = oma + alpha * (1.0f - __expf(-tau * md));
        scale = fminf(fmaxf(scale, 0.1f), 10.0f);

        // epilogue straight from f16 row registers
        float* outr = out + (size_t)row * D;
        #pragma unroll
        for (int c = 0; c < 8; ++c) {
            float4 o;
            o.x = gelu_tanh_fast((float)xh[2 * c][0]     * scale);
            o.y = gelu_tanh_fast((float)xh[2 * c][1]     * scale);
            o.z = gelu_tanh_fast((float)xh[2 * c + 1][0] * scale);
            o.w = gelu_tanh_fast((float)xh[2 * c + 1][1] * scale);
            *(float4*)(outr + (c * 64 + lane) * 4) = o;
        }
    }
}

extern "C" void kernel_launch(void* const* d_in, const int* in_sizes, int n_in,
                              void* d_out, int out_size, void* d_ws, size_t ws_size,
                              hipStream_t stream) {
    const float* x  = (const float*)d_in[0];
    const float* P  = (const float*)d_in[1];
    const float* lt = (const float*)d_in[2];
    const float* lb = (const float*)d_in[3];
    float* out = (float*)d_out;

    const int nrows = in_sizes[0] / D;             // 32768
    const int waves = BLOCK / 64;                  // 8
    int grid = (nrows + waves * RPW - 1) / (waves * RPW);   // 1024

    novelty_gelu_wave<<<grid, BLOCK, 0, stream>>>(x, P, lt, lb, out, nrows);
}

// Round 16
// 112.317 us; speedup vs baseline: 2.9546x; 1.8436x over previous
//
#include <hip/hip_runtime.h>
#include <math.h>

#define D 2048
#define K 8
#define BLOCK 512     // 8 independent waves; wave owns a whole row (lane = 32 cols)
#define RPW 4         // contiguous rows per wave

typedef __fp16 h2 __attribute__((ext_vector_type(2)));
typedef __fp16 h4 __attribute__((ext_vector_type(4)));

__device__ __forceinline__ float rcp_fast(float x) {
    return __builtin_amdgcn_rcpf(x);
}

#if __has_builtin(__builtin_amdgcn_fdot2)
#define FDOT2(a, b, c) __builtin_amdgcn_fdot2((a), (b), (c), false)
#else
__device__ __forceinline__ float fdot2_emul(h2 a, h2 b, float c) {
    return fmaf((float)a[0], (float)b[0], fmaf((float)a[1], (float)b[1], c));
}
#define FDOT2 fdot2_emul
#endif

// 0.5*y*(1+tanh(c*(y+0.044715*y^3))) == y * sigmoid(2c*(y+0.044715*y^3))
__device__ __forceinline__ float gelu_tanh_fast(float y) {
    const float nc = -2.3022078977f; // -2*sqrt(2/pi)*log2(e)
    float w = y * fmaf(0.044715f, y * y, 1.0f);
    return y * rcp_fast(1.0f + exp2f(nc * w));
}

__device__ __forceinline__ float dot4f(const float4& a, const float4& b) {
    return fmaf(a.w, b.w, fmaf(a.z, b.z, fmaf(a.y, b.y, a.x * b.x)));
}

// Fold step: combine slots x (bit=0) and y (bit=1) across lanes differing in `m`.
#define FOLDSTEP(x, y, m)                                   \
    {                                                       \
        float _k = (lane & (m)) ? (y) : (x);                \
        float _o = (lane & (m)) ? (x) : (y);                \
        x = _k + __shfl_xor(_o, (m));                       \
    }

__global__ __launch_bounds__(BLOCK, 2)   // loose cap (256): allocator never forced
void novelty_gelu_wave(const float* __restrict__ x,
                       const float* __restrict__ P,
                       const float* __restrict__ plog_tau,
                       const float* __restrict__ plog_blend,
                       float* __restrict__ out,
                       int nrows)
{
    __shared__ h4    pf[K * 512];   // 32 KB: proto k, chunk-lane h4 index
    __shared__ float s_inv[K];

    const int tid  = threadIdx.x;
    const int wave = tid >> 6;
    const int lane = tid & 63;

    // ---- prototype inv-norms: wave w handles proto w (8 waves = 8 protos)
    {
        const float* pr = P + wave * D;
        float s = 0.f;
        #pragma unroll
        for (int j = 0; j < 8; ++j) {
            float4 p = *(const float4*)(pr + (j * 64 + lane) * 4);
            s += dot4f(p, p);
        }
        #pragma unroll
        for (int m = 1; m < 64; m <<= 1) s += __shfl_xor(s, m);
        if (lane == 0) s_inv[wave] = 1.0f / fmaxf(sqrtf(s), 1e-8f);
    }
    __syncthreads();

    // ---- pf fill: thread t writes proto k's h4 chunk t (lane-stride-8B, dense)
    #pragma unroll
    for (int k = 0; k < K; ++k) {
        const float inv = s_inv[k];
        float4 p = *(const float4*)(P + k * D + tid * 4);
        h2 lo = __builtin_amdgcn_cvt_pkrtz(p.x * inv, p.y * inv);
        h2 hi = __builtin_amdgcn_cvt_pkrtz(p.z * inv, p.w * inv);
        pf[k * 512 + tid] = __builtin_shufflevector(lo, hi, 0, 1, 2, 3);
    }
    __syncthreads();
    // ---- from here on: every wave fully independent, no barriers, no LDS writes

    const float tau   = __expf(plog_tau[0]);
    const float alpha = 1.0f / (1.0f + __expf(-plog_blend[0]));
    const float oma   = 1.0f - alpha;

    const int wid = blockIdx.x * (BLOCK / 64) + wave;
    int row = wid * RPW;
    int limit = row + RPW;
    if (limit > nrows) limit = nrows;

    for (; row < limit; ++row) {
        const float* xr = x + (size_t)row * D;

        h2 xh[16];
        float ssq = 0.f;
        float dt[K];
        #pragma unroll
        for (int k = 0; k < K; ++k) dt[k] = 0.f;

        // two half-row groups: 4 loads in flight (16 transient VGPR), then cvt+dot
        #pragma unroll
        for (int g = 0; g < 2; ++g) {
            float4 v[4];
            #pragma unroll
            for (int j = 0; j < 4; ++j)
                v[j] = *(const float4*)(xr + ((g * 4 + j) * 64 + lane) * 4);

            #pragma unroll
            for (int j = 0; j < 4; ++j) {
                const int c = g * 4 + j;
                h2 xlo = __builtin_amdgcn_cvt_pkrtz(v[j].x, v[j].y);
                h2 xhi = __builtin_amdgcn_cvt_pkrtz(v[j].z, v[j].w);
                xh[2 * c]     = xlo;
                xh[2 * c + 1] = xhi;
                ssq = FDOT2(xlo, xlo, ssq);
                ssq = FDOT2(xhi, xhi, ssq);
                #pragma unroll
                for (int k = 0; k < K; ++k) {
                    h4 p  = pf[k * 512 + c * 64 + lane];
                    h2 lo = __builtin_shufflevector(p, p, 0, 1);
                    h2 hi = __builtin_shufflevector(p, p, 2, 3);
                    dt[k] = FDOT2(xlo, lo, dt[k]);
                    dt[k] = FDOT2(xhi, hi, dt[k]);
                }
            }
        }

        // wave-local full reduction: 19 swizzles, no LDS, no barrier
        FOLDSTEP(dt[0], dt[1], 1);
        FOLDSTEP(dt[2], dt[3], 1);
        FOLDSTEP(dt[4], dt[5], 1);
        FOLDSTEP(dt[6], dt[7], 1);
        FOLDSTEP(dt[0], dt[2], 2);
        FOLDSTEP(dt[4], dt[6], 2);
        FOLDSTEP(dt[0], dt[4], 4);
        float vd = dt[0];
        vd += __shfl_xor(vd, 8);
        vd += __shfl_xor(vd, 16);
        vd += __shfl_xor(vd, 32);              // lane l: full-row dot[l&7]
        float dmax = vd;                        // max over the 8 slots
        dmax = fmaxf(dmax, __shfl_xor(dmax, 1));
        dmax = fmaxf(dmax, __shfl_xor(dmax, 2));
        dmax = fmaxf(dmax, __shfl_xor(dmax, 4));
        #pragma unroll
        for (int m = 1; m < 64; m <<= 1) ssq += __shfl_xor(ssq, m);

        const float inv_nx = 1.0f / fmaxf(sqrtf(ssq), 1e-8f);
        float sim = fminf(1.0f, fmaxf(-1.0f, dmax * inv_nx));
        float md  = fminf(fmaxf(1.0f - sim, 0.0f), 2.0f);
        float scale = oma + alpha * (1.0f - __expf(-tau * md));
        scale = fminf(fmaxf(scale, 0.1f), 10.0f);

        // epilogue straight from f16 row registers
        float* outr = out + (size_t)row * D;
        #pragma unroll
        for (int c = 0; c < 8; ++c) {
            float4 o;
            o.x = gelu_tanh_fast((float)xh[2 * c][0]     * scale);
            o.y = gelu_tanh_fast((float)xh[2 * c][1]     * scale);
            o.z = gelu_tanh_fast((float)xh[2 * c + 1][0] * scale);
            o.w = gelu_tanh_fast((float)xh[2 * c + 1][1] * scale);
            *(float4*)(outr + (c * 64 + lane) * 4) = o;
        }
    }
}

extern "C" void kernel_launch(void* const* d_in, const int* in_sizes, int n_in,
                              void* d_out, int out_size, void* d_ws, size_t ws_size,
                              hipStream_t stream) {
    const float* x  = (const float*)d_in[0];
    const float* P  = (const float*)d_in[1];
    const float* lt = (const float*)d_in[2];
    const float* lb = (const float*)d_in[3];
    float* out = (float*)d_out;

    const int nrows = in_sizes[0] / D;             // 32768
    const int waves = BLOCK / 64;                  // 8
    int grid = (nrows + waves * RPW - 1) / (waves * RPW);   // 1024

    novelty_gelu_wave<<<grid, BLOCK, 0, stream>>>(x, P, lt, lb, out, nrows);
}